// Round 18
// baseline (175.731 us; speedup 1.0000x reference)
//
#include <hip/hip_runtime.h>
#include <hip/hip_bf16.h>
#include <stdint.h>

#define EPSV 1e-6f
#define N1 4096
#define N2 4096
#define DD 1024
#define NLAYERS 3
#define KKC 10

typedef __bf16 bf16_t;
typedef __bf16 bf16x8 __attribute__((ext_vector_type(8)));
typedef float f32x4 __attribute__((ext_vector_type(4)));
typedef long longx2 __attribute__((ext_vector_type(2)));

#define ZSCALE 256.0f
#define WSCALE 64.0f
#define INVSCALE 6.103515625e-05f   // 1/(ZSCALE*WSCALE)

// bins: 32 i-bins x 32 j-bins (128x128 tiles) = 1024 per layer, 3072 total
#define NBIN_L 1024
#define NBIN_T (NLAYERS*NBIN_L)

__device__ __forceinline__ float softplus_fast(float x) {
  return fmaxf(x, 0.f) + __logf(1.f + __expf(-fabsf(x)));
}
__device__ __forceinline__ float softplus_ref(float x) {
  return fmaxf(x, 0.f) + log1pf(expf(-fabsf(x)));
}
__device__ __forceinline__ float wredsum(float x) {
  #pragma unroll
  for (int o = 32; o; o >>= 1) x += __shfl_xor(x, o, 64);
  return x;
}
__device__ __forceinline__ float wredmax(float x) {
  #pragma unroll
  for (int o = 32; o; o >>= 1) x = fmaxf(x, __shfl_xor(x, o, 64));
  return x;
}
__device__ __forceinline__ void global_load_lds16(const void* g, void* l) {
  __builtin_amdgcn_global_load_lds(
      (const __attribute__((address_space(1))) uint32_t*)g,
      (__attribute__((address_space(3))) uint32_t*)l, 16, 0, 0);
}

// OCP e4m3fn encode, x in [0, 448], RNE. Denormal path: value = k*2^-9.
__device__ __forceinline__ uint32_t enc_e4m3(float x) {
  if (x < 0.015625f) return (uint32_t)__float2int_rn(x * 512.0f);
  uint32_t u = __float_as_uint(x);
  u += 0x7FFFFu + ((u >> 20) & 1u);
  return (((u >> 23) - 120u) << 3) | ((u >> 20) & 7u);
}

// ---------------- prep_small ----------------
__global__ __launch_bounds__(256) void prep_small(
    const float* __restrict__ lz, const float* __restrict__ lw,
    const float* __restrict__ gamma, const float* __restrict__ delta,
    const float* __restrict__ pks, const float* __restrict__ Lp,
    float* __restrict__ consts, float* __restrict__ a_tab, float* __restrict__ b_tab,
    float* __restrict__ g_tab, float* __restrict__ d_tab,
    uint32_t* __restrict__ hist, float* __restrict__ out)
{
  int n = blockIdx.x * blockDim.x + threadIdx.x;
  float Lv = softplus_ref(Lp[0]);
  if (n == 0) out[0] = 0.f;
  if (n < NBIN_T) hist[n] = 0u;
  if (n < N1) {
    float z0 = lz[n*3], z1 = lz[n*3+1], z2 = lz[n*3+2];
    float m = fmaxf(z0, fmaxf(z1, z2));
    float e0 = expf(z0-m), e1 = expf(z1-m), e2 = expf(z2-m);
    float inv = 1.f/(e0+e1+e2);
    a_tab[0*N1+n] = e0*inv*Lv; a_tab[1*N1+n] = e1*inv*Lv; a_tab[2*N1+n] = e2*inv*Lv;
    float w0 = lw[n*3], w1 = lw[n*3+1], w2 = lw[n*3+2];
    m = fmaxf(w0, fmaxf(w1, w2));
    e0 = expf(w0-m); e1 = expf(w1-m); e2 = expf(w2-m);
    inv = 1.f/(e0+e1+e2);
    b_tab[0*N2+n] = e0*inv+EPSV; b_tab[1*N2+n] = e1*inv+EPSV; b_tab[2*N2+n] = e2*inv+EPSV;
    #pragma unroll
    for (int k = 0; k < 3; ++k) {
      g_tab[k*N1+n] = gamma[n*3+k];
      d_tab[k*N2+n] = delta[n*3+k];
    }
  }
  if (n < NLAYERS) {
    float p[KKC+1]; float m = -1e30f;
    for (int k = 0; k <= KKC; ++k) { p[k] = pks[n*(KKC+1)+k]; m = fmaxf(m, p[k]); }
    float s = 0.f;
    for (int k = 0; k <= KKC; ++k) { p[k] = expf(p[k]-m); s += p[k]; }
    float inv = 1.f/s;
    for (int k = 0; k <= KKC; ++k) consts[8 + n*(KKC+1) + k] = p[k]*inv;
    consts[n] = p[0]*inv + EPSV*(1.f - p[0]*inv);
  }
}

// ---------------- edge binning ----------------
#define EPB 2048

__global__ __launch_bounds__(256) void edge_hist(
    const int* __restrict__ is_, const int* __restrict__ js_,
    uint32_t* __restrict__ hist, int E)
{
  __shared__ uint32_t h[NBIN_L];
  const int lay = blockIdx.y;
  const int t = threadIdx.x;
  #pragma unroll
  for (int i = 0; i < NBIN_L/256; ++i) h[t + i*256] = 0u;
  __syncthreads();
  const int e0 = blockIdx.x * EPB;
  const int e1 = min(e0 + EPB, E);
  for (int e = e0 + t; e < e1; e += 256) {
    int i = is_[(size_t)lay*E + e], j = js_[(size_t)lay*E + e];
    atomicAdd(&h[(i>>7)*32 + (j>>7)], 1u);
  }
  __syncthreads();
  #pragma unroll
  for (int i = 0; i < NBIN_L/256; ++i)
    if (h[t + i*256]) atomicAdd(&hist[lay*NBIN_L + t + i*256], h[t + i*256]);
}

// per-layer scan: block = layer; off base = layer*E (cumsum continuous across layers)
__global__ __launch_bounds__(256) void edge_scan(
    const uint32_t* __restrict__ hist, uint32_t* __restrict__ off,
    uint32_t* __restrict__ cursor, int E)
{
  __shared__ uint32_t sa[NBIN_L], sb[NBIN_L];
  const int lay = blockIdx.x;
  const int t = threadIdx.x;
  const uint32_t base = (uint32_t)lay * (uint32_t)E;
  for (int i = t; i < NBIN_L; i += 256) sa[i] = hist[lay*NBIN_L + i];
  __syncthreads();
  uint32_t* src = sa; uint32_t* dst = sb;
  for (int s = 1; s < NBIN_L; s <<= 1) {
    for (int i = t; i < NBIN_L; i += 256) dst[i] = src[i] + (i >= s ? src[i-s] : 0u);
    __syncthreads();
    uint32_t* tmp = src; src = dst; dst = tmp;
  }
  for (int i = t; i < NBIN_L; i += 256) {
    uint32_t ex = base + (i ? src[i-1] : 0u);
    off[lay*NBIN_L + i] = ex; cursor[lay*NBIN_L + i] = ex;
  }
  if (t == 0 && lay == NLAYERS-1) off[NBIN_T] = base + src[NBIN_L-1];
}

__global__ __launch_bounds__(256) void edge_scatter(
    const int* __restrict__ is_, const int* __restrict__ js_,
    uint32_t* __restrict__ cursor, uint16_t* __restrict__ ebuf, int E)
{
  __shared__ uint32_t h[NBIN_L];
  __shared__ uint32_t basev[NBIN_L];
  const int lay = blockIdx.y;
  const int t = threadIdx.x;
  #pragma unroll
  for (int i = 0; i < NBIN_L/256; ++i) h[t + i*256] = 0u;
  __syncthreads();
  const int e0 = blockIdx.x * EPB;
  const int e1 = min(e0 + EPB, E);
  for (int e = e0 + t; e < e1; e += 256) {
    int i = is_[(size_t)lay*E + e], j = js_[(size_t)lay*E + e];
    atomicAdd(&h[(i>>7)*32 + (j>>7)], 1u);
  }
  __syncthreads();
  #pragma unroll
  for (int i = 0; i < NBIN_L/256; ++i) {
    int b = t + i*256;
    basev[b] = h[b] ? atomicAdd(&cursor[lay*NBIN_L + b], h[b]) : 0u;
    h[b] = 0u;
  }
  __syncthreads();
  for (int e = e0 + t; e < e1; e += 256) {
    int i = is_[(size_t)lay*E + e], j = js_[(size_t)lay*E + e];
    int b = (i>>7)*32 + (j>>7);
    uint32_t r = atomicAdd(&h[b], 1u);
    ebuf[basev[b] + r] = (uint16_t)(((i & 127) << 7) | (j & 127));
  }
}

// ---------------- prep_rows: wave-per-row softmax (+pyramid), fp8 PERMUTED output ----------------
__global__ __launch_bounds__(256) void prep_rows(
    const float* __restrict__ us, const float* __restrict__ vs,
    uint8_t* __restrict__ zt8, uint8_t* __restrict__ wt8, size_t lstride,
    const float* __restrict__ consts, int layer0)
{
  const int t = threadIdx.x, w = t >> 6, l = t & 63;
  const int n = blockIdx.x*4 + w;
  const int layer = layer0 + blockIdx.y;
  const int zmode = (blockIdx.z == 0);
  const float* src = (zmode ? us : vs) + ((size_t)layer*N1 + n)*DD + l*16;
  uint8_t* drow = (zmode ? zt8 : wt8) + (size_t)blockIdx.y*lstride + (size_t)n*1024;
  const int p0 = (l>>2)*64 + ((l&1)*2)*16 + ((l&3)>>1)*8;

  float e[16];
  {
    const float4* s4 = (const float4*)src;
    float4 u0 = s4[0], u1 = s4[1], u2 = s4[2], u3 = s4[3];
    e[0]=u0.x; e[1]=u0.y; e[2]=u0.z; e[3]=u0.w;
    e[4]=u1.x; e[5]=u1.y; e[6]=u1.z; e[7]=u1.w;
    e[8]=u2.x; e[9]=u2.y; e[10]=u2.z; e[11]=u2.w;
    e[12]=u3.x; e[13]=u3.y; e[14]=u3.z; e[15]=u3.w;
  }
  float mx = e[0];
  #pragma unroll
  for (int i = 1; i < 16; ++i) mx = fmaxf(mx, e[i]);
  mx = wredmax(mx);
  float s = 0.f;
  #pragma unroll
  for (int i = 0; i < 16; ++i) { e[i] = __expf(e[i]-mx); s += e[i]; }
  s = wredsum(s);
  float inv = 1.f/s;
  #pragma unroll
  for (int i = 0; i < 16; ++i) e[i] *= inv;

  uint32_t b4[4] = {0u, 0u, 0u, 0u};
  if (!zmode) {
    #pragma unroll
    for (int i = 0; i < 16; ++i)
      b4[i>>2] |= enc_e4m3(e[i]*WSCALE) << ((i&3)*8);
  } else {
    float s1[8], s2[4], s3[2], s4v;
    #pragma unroll
    for (int i = 0; i < 8; ++i) s1[i] = e[2*i] + e[2*i+1];
    #pragma unroll
    for (int i = 0; i < 4; ++i) s2[i] = s1[2*i] + s1[2*i+1];
    s3[0] = s2[0]+s2[1]; s3[1] = s2[2]+s2[3];
    s4v = s3[0]+s3[1];
    float s5 = s4v + __shfl_xor(s4v, 1, 64);
    float s6 = s5  + __shfl_xor(s5, 2, 64);
    float s7 = s6  + __shfl_xor(s6, 4, 64);
    float s8 = s7  + __shfl_xor(s7, 8, 64);
    float s9 = s8  + __shfl_xor(s8, 16, 64);
    const float* pk = consts + 8 + layer*(KKC+1);
    const float base = pk[4]*s4v + pk[5]*s5 + pk[6]*s6 + pk[7]*s7 + pk[8]*s8 + pk[9]*s9;
    const float p1 = pk[1], p2 = pk[2], p3 = pk[3], p10 = pk[10];
    #pragma unroll
    for (int i = 0; i < 16; ++i) {
      float v = p10*e[i] + p1*s1[i>>1] + p2*s2[i>>2] + p3*s3[i>>3] + base;
      b4[i>>2] |= enc_e4m3(v*ZSCALE) << ((i&3)*8);
    }
  }
  uint64_t u0 = (uint64_t)b4[0] | ((uint64_t)b4[1] << 32);
  uint64_t u1 = (uint64_t)b4[2] | ((uint64_t)b4[3] << 32);
  *(uint64_t*)(drow + p0)      = u0;
  *(uint64_t*)(drow + p0 + 16) = u1;
}

// ---------------- 128x128 fp8 GEMM: A direct-from-L2 to regs, B via LDS ----------------
// 4 waves (2Mx2N), wave tile 64x64, acc[4][4]. LDS stages B ONLY: buf = 8KB, 2 bufs = 16KB;
// LDS alloc 32KB (epilogue C reuses). A fragments (16B/lane, permuted-contiguous) are
// loaded straight from global (L2-hot; bi-slow/bj-fast mapping keeps XCD A-working-set
// ~0.5MB), double-buffered in ar[2][4] (compile-time u&1 under full unroll).
// Per u: {vmcnt(0) [retires stageB(u)+loadA(u), both issued at u-1 => full iter of cover];
//   barrier; issue stageB(u+1); issue loadA(u+1); 4x ds_read B; 32 MFMA}.
// Mechanism: halves LDS pipe traffic (model: LDS 2336->~1000 cyc/round vs MFMA ~830).
__global__ __launch_bounds__(256, 3) void gemm_fused(
    const uint8_t* __restrict__ Az8, size_t zls,
    const uint8_t* __restrict__ Bw8, size_t wls,
    const float* __restrict__ a_tab, const float* __restrict__ b_tab,
    const float* __restrict__ g_tab, const float* __restrict__ d_tab,
    const float* __restrict__ consts, int layer0,
    const uint32_t* __restrict__ eoff, const uint16_t* __restrict__ ebuf,
    float* __restrict__ out)
{
  extern __shared__ char lds[];                // 32KB: 2 x 8KB B-bufs; epilogue C reuses all
  const int t = threadIdx.x;
  const int w = t >> 6, l = t & 63;
  const int wm = w >> 1, wn = w & 1;           // 2x2 wave grid; wave tile 64x64
  const int fr = l & 15, fq = l >> 4;

  // T1: bijective XCD swizzle; bi SLOW / bj FAST so concurrent XCD blocks share A rows in L2
  const int nbx = gridDim.x, nby = gridDim.y;   // 32, 32
  int lid = blockIdx.x + nbx*(blockIdx.y + nby*blockIdx.z);
  const int nblk = nbx*nby*gridDim.z;
  const int cpx = nblk >> 3;
  int nid = (lid & 7)*cpx + (lid >> 3);
  const int bz = nid / (nbx*nby);
  const int rem = nid % (nbx*nby);
  const int bj = rem % nby, bi = rem / nby;     // bj fast-varying

  const int i0 = bi*128, j0 = bj*128;
  const int layer = layer0 + bz;
  Az8 += (size_t)bz*zls + (size_t)i0*1024;
  Bw8 += (size_t)bz*wls + (size_t)j0*1024;

  f32x4 acc[4][4];
  f32x4 zero = {0.f, 0.f, 0.f, 0.f};
  #pragma unroll
  for (int m = 0; m < 4; ++m)
    #pragma unroll
    for (int nn = 0; nn < 4; ++nn) acc[m][nn] = zero;

  // B stage-side involution (verified R10-R17)
  const int go = (l & 7) ^ (l >> 3);
  const size_t s_off = (size_t)((l >> 3)*2 + (go >> 2))*1024 + (size_t)(go & 3)*16;
  // B read-side slot (conflict-free b128 pattern, verified R11-R17); B region at LDS offset 0
  const int slot = (((fr & 1) << 2) + fq) ^ (fr >> 1);
  const int bbase = wn*4096 + (fr>>1)*128 + slot*16;          // + nn*1024, + buf*8192

  // A per-lane global base: row = wm*64 + m*16 + fr, permuted 16B chunk at +fq*16
  const uint8_t* pA = Az8 + (size_t)(wm*64 + fr)*1024 + (size_t)fq*16;

  longx2 ar[2][4], br2[4];

#define STG_B(tile) do { \
    char* _d = lds + ((tile)&1)*8192 + w*2048; \
    const uint8_t* _s = Bw8 + (size_t)(w*32)*1024 + (size_t)(tile)*64 + s_off; \
    global_load_lds16(_s, _d); \
    global_load_lds16(_s + (size_t)16*1024, _d + 1024); \
  } while (0)
#define LOAD_A(buf, tile) do { \
    _Pragma("unroll") for (int m = 0; m < 4; ++m) \
      ar[buf][m] = *(const longx2*)(pA + (size_t)m*16384 + (size_t)(tile)*64); \
  } while (0)

  // prologue: stage B(0) into buf0; load A(0) into ar[0]
  STG_B(0);
  LOAD_A(0, 0);

  #pragma unroll
  for (int u = 0; u < 16; ++u) {
    const int cb = (u & 1)*8192;
    asm volatile("s_waitcnt vmcnt(0)" ::: "memory");   // stageB(u) + loadA(u) landed
    asm volatile("s_barrier" ::: "memory");            // B(u) visible block-wide
    if (u < 15) {
      STG_B(u+1);                                      // -> buf[(u+1)&1]; readers retired (barrier)
      LOAD_A((u+1)&1, u+1);
    }
    #pragma unroll
    for (int j = 0; j < 4; ++j)
      br2[j] = *(const longx2*)(lds + cb + bbase + j*1024);
    __builtin_amdgcn_s_setprio(1);
    #pragma unroll
    for (int i = 0; i < 4; ++i)
      #pragma unroll
      for (int j = 0; j < 4; ++j) {
        acc[i][j] = __builtin_amdgcn_mfma_f32_16x16x32_fp8_fp8(
            ar[u&1][i].x, br2[j].x, acc[i][j], 0, 0, 0);
        acc[i][j] = __builtin_amdgcn_mfma_f32_16x16x32_fp8_fp8(
            ar[u&1][i].y, br2[j].y, acc[i][j], 0, 0, 0);
      }
    __builtin_amdgcn_s_setprio(0);
  }
#undef STG_B
#undef LOAD_A

  // ---- epilogue: C (128x128 bf16 = 32KB) into LDS; dense softplus-sum + binned sparse ----
  __syncthreads();                       // all waves done reading B bufs
  const float cc = consts[layer];
  {
    // row = wm*64 + m*16 + fq*4 + r ; col = wn*64 + nn*16 + fr ; byte = row*256 + col*2
    char* cbase = lds + wm*16384 + fq*1024 + wn*128 + fr*2;
    #pragma unroll
    for (int m = 0; m < 4; ++m)
      #pragma unroll
      for (int nn = 0; nn < 4; ++nn)
        #pragma unroll
        for (int r = 0; r < 4; ++r)
          *(bf16_t*)(cbase + m*4096 + r*256 + nn*32) =
              (bf16_t)(acc[m][nn][r]*INVSCALE + cc);
  }
  __syncthreads();

  const float* at = a_tab + layer*N1;
  const float* bt = b_tab + layer*N2;
  const float* gt = g_tab + layer*N1;
  const float* dt = d_tab + layer*N2;
  float dsum = 0.f;
  #pragma unroll
  for (int i = 0; i < 8; ++i) {
    const int id = t + i*256;            // 2048 chunks of 16B
    const int row = id >> 4, g = id & 15;
    bf16x8 v = *(const bf16x8*)(lds + row*256 + g*16);
    const int grow = i0 + row, gcol = j0 + g*8;
    const float av = at[grow], gv = gt[grow];
    float4 b0 = *(const float4*)(bt + gcol), b1 = *(const float4*)(bt + gcol + 4);
    float4 d0 = *(const float4*)(dt + gcol), d1 = *(const float4*)(dt + gcol + 4);
    float bb[8] = {b0.x,b0.y,b0.z,b0.w,b1.x,b1.y,b1.z,b1.w};
    float dd[8] = {d0.x,d0.y,d0.z,d0.w,d1.x,d1.y,d1.z,d1.w};
    #pragma unroll
    for (int e2 = 0; e2 < 8; ++e2) {
      float x = av*bb[e2]*(float)v[e2] + gv + dd[e2];
      float sp = softplus_fast(x);
      dsum += (grow != gcol + e2) ? sp : 0.f;
    }
  }
  const int bin = bz*NBIN_L + bi*32 + bj;
  const uint32_t e0 = eoff[bin], e1 = eoff[bin+1];
  float ssum = 0.f;
  for (uint32_t e = e0 + (uint32_t)t; e < e1; e += 256u) {
    const int pk2 = ebuf[e];
    const int li = pk2 >> 7, lj = pk2 & 127;
    float dc = (float)*(const bf16_t*)(lds + li*256 + lj*2);
    ssum += at[i0+li]*bt[j0+lj]*dc + gt[i0+li] + dt[j0+lj];
  }
  float tot = wredsum(ssum - dsum);
  __syncthreads();
  if (l == 0) ((float*)lds)[w] = tot;
  __syncthreads();
  if (t == 0) {
    const float* r = (const float*)lds;
    atomicAdd(out, r[0] + r[1] + r[2] + r[3]);   // ll += z_pdist2 - z_pdist1
  }
}

extern "C" void kernel_launch(void* const* d_in, const int* in_sizes, int n_in,
                              void* d_out, int out_size, void* d_ws, size_t ws_size,
                              hipStream_t stream) {
  const float* us    = (const float*)d_in[0];
  const float* vs    = (const float*)d_in[1];
  const float* gamma = (const float*)d_in[2];
  const float* delta = (const float*)d_in[3];
  const float* lz    = (const float*)d_in[4];
  const float* lw    = (const float*)d_in[5];
  const float* pks   = (const float*)d_in[6];
  const float* Lp    = (const float*)d_in[7];
  const int*   sis   = (const int*)d_in[8];
  const int*   sjs   = (const int*)d_in[9];
  float* out = (float*)d_out;
  char*  ws  = (char*)d_ws;
  const int E = in_sizes[8] / NLAYERS;

  size_t p = 0;
  float* consts = (float*)(ws + p); p += 1024;
  float* a_tab  = (float*)(ws + p); p += (size_t)NLAYERS*N1*4;
  float* b_tab  = (float*)(ws + p); p += (size_t)NLAYERS*N2*4;
  float* g_tab  = (float*)(ws + p); p += (size_t)NLAYERS*N1*4;
  float* d_tab  = (float*)(ws + p); p += (size_t)NLAYERS*N2*4;
  uint32_t* hist   = (uint32_t*)(ws + p); p += 4096*4;
  uint32_t* eoff   = (uint32_t*)(ws + p); p += 4096*4;
  uint32_t* cursor = (uint32_t*)(ws + p); p += 4096*4;
  uint16_t* ebuf   = (uint16_t*)(ws + p); p += (size_t)NLAYERS*E*2;
  p = (p + 4095) & ~(size_t)4095;
  uint8_t* zt8 = (uint8_t*)(ws + p); p += (size_t)NLAYERS*N1*1024;
  uint8_t* wt8 = (uint8_t*)(ws + p); p += (size_t)NLAYERS*N2*1024;
  if (ws_size < p) return;
  const size_t ZLS = (size_t)N1*1024;
  const size_t LDSB = 32768;
  const int nebl = (E + EPB - 1) / EPB;

  prep_small<<<(N1+255)/256, 256, 0, stream>>>(lz, lw, gamma, delta, pks, Lp,
                                               consts, a_tab, b_tab, g_tab, d_tab,
                                               hist, out);
  edge_hist<<<dim3(nebl, NLAYERS), 256, 0, stream>>>(sis, sjs, hist, E);
  edge_scan<<<NLAYERS, 256, 0, stream>>>(hist, eoff, cursor, E);
  edge_scatter<<<dim3(nebl, NLAYERS), 256, 0, stream>>>(sis, sjs, cursor, ebuf, E);
  prep_rows<<<dim3(N1/4, NLAYERS, 2), 256, 0, stream>>>(us, vs, zt8, wt8, ZLS, consts, 0);
  gemm_fused<<<dim3(32,32,NLAYERS), 256, LDSB, stream>>>(
      zt8, ZLS, wt8, ZLS, a_tab, b_tab, g_tab, d_tab, consts, 0, eoff, ebuf, out);
}

// Round 19
// 132.810 us; speedup vs baseline: 1.3232x; 1.3232x over previous
//
#include <hip/hip_runtime.h>
#include <hip/hip_bf16.h>
#include <stdint.h>

#define EPSV 1e-6f
#define N1 4096
#define N2 4096
#define DD 1024
#define NLAYERS 3
#define KKC 10

typedef __bf16 bf16_t;
typedef __bf16 bf16x8 __attribute__((ext_vector_type(8)));
typedef float f32x4 __attribute__((ext_vector_type(4)));
typedef long longx2 __attribute__((ext_vector_type(2)));

#define ZSCALE 256.0f
#define WSCALE 64.0f
#define INVSCALE 6.103515625e-05f   // 1/(ZSCALE*WSCALE)

// bins: 32 i-bins x 32 j-bins (128x128 tiles) = 1024 per layer, 3072 total
#define NBIN_L 1024
#define NBIN_T (NLAYERS*NBIN_L)

__device__ __forceinline__ float softplus_fast(float x) {
  return fmaxf(x, 0.f) + __logf(1.f + __expf(-fabsf(x)));
}
__device__ __forceinline__ float softplus_ref(float x) {
  return fmaxf(x, 0.f) + log1pf(expf(-fabsf(x)));
}
__device__ __forceinline__ float wredsum(float x) {
  #pragma unroll
  for (int o = 32; o; o >>= 1) x += __shfl_xor(x, o, 64);
  return x;
}
__device__ __forceinline__ float wredmax(float x) {
  #pragma unroll
  for (int o = 32; o; o >>= 1) x = fmaxf(x, __shfl_xor(x, o, 64));
  return x;
}
__device__ __forceinline__ void global_load_lds16(const void* g, void* l) {
  __builtin_amdgcn_global_load_lds(
      (const __attribute__((address_space(1))) uint32_t*)g,
      (__attribute__((address_space(3))) uint32_t*)l, 16, 0, 0);
}

// OCP e4m3fn encode, x in [0, 448], RNE. Denormal path: value = k*2^-9.
__device__ __forceinline__ uint32_t enc_e4m3(float x) {
  if (x < 0.015625f) return (uint32_t)__float2int_rn(x * 512.0f);
  uint32_t u = __float_as_uint(x);
  u += 0x7FFFFu + ((u >> 20) & 1u);
  return (((u >> 23) - 120u) << 3) | ((u >> 20) & 7u);
}

// ---------------- prep_small ----------------
__global__ __launch_bounds__(256) void prep_small(
    const float* __restrict__ lz, const float* __restrict__ lw,
    const float* __restrict__ gamma, const float* __restrict__ delta,
    const float* __restrict__ pks, const float* __restrict__ Lp,
    float* __restrict__ consts, float* __restrict__ a_tab, float* __restrict__ b_tab,
    float* __restrict__ g_tab, float* __restrict__ d_tab,
    uint32_t* __restrict__ hist, float* __restrict__ out)
{
  int n = blockIdx.x * blockDim.x + threadIdx.x;
  float Lv = softplus_ref(Lp[0]);
  if (n == 0) out[0] = 0.f;
  if (n < NBIN_T) hist[n] = 0u;
  if (n < N1) {
    float z0 = lz[n*3], z1 = lz[n*3+1], z2 = lz[n*3+2];
    float m = fmaxf(z0, fmaxf(z1, z2));
    float e0 = expf(z0-m), e1 = expf(z1-m), e2 = expf(z2-m);
    float inv = 1.f/(e0+e1+e2);
    a_tab[0*N1+n] = e0*inv*Lv; a_tab[1*N1+n] = e1*inv*Lv; a_tab[2*N1+n] = e2*inv*Lv;
    float w0 = lw[n*3], w1 = lw[n*3+1], w2 = lw[n*3+2];
    m = fmaxf(w0, fmaxf(w1, w2));
    e0 = expf(w0-m); e1 = expf(w1-m); e2 = expf(w2-m);
    inv = 1.f/(e0+e1+e2);
    b_tab[0*N2+n] = e0*inv+EPSV; b_tab[1*N2+n] = e1*inv+EPSV; b_tab[2*N2+n] = e2*inv+EPSV;
    #pragma unroll
    for (int k = 0; k < 3; ++k) {
      g_tab[k*N1+n] = gamma[n*3+k];
      d_tab[k*N2+n] = delta[n*3+k];
    }
  }
  if (n < NLAYERS) {
    float p[KKC+1]; float m = -1e30f;
    for (int k = 0; k <= KKC; ++k) { p[k] = pks[n*(KKC+1)+k]; m = fmaxf(m, p[k]); }
    float s = 0.f;
    for (int k = 0; k <= KKC; ++k) { p[k] = expf(p[k]-m); s += p[k]; }
    float inv = 1.f/s;
    for (int k = 0; k <= KKC; ++k) consts[8 + n*(KKC+1) + k] = p[k]*inv;
    consts[n] = p[0]*inv + EPSV*(1.f - p[0]*inv);
  }
}

// ---------------- edge binning ----------------
#define EPB 2048

__global__ __launch_bounds__(256) void edge_hist(
    const int* __restrict__ is_, const int* __restrict__ js_,
    uint32_t* __restrict__ hist, int E)
{
  __shared__ uint32_t h[NBIN_L];
  const int lay = blockIdx.y;
  const int t = threadIdx.x;
  #pragma unroll
  for (int i = 0; i < NBIN_L/256; ++i) h[t + i*256] = 0u;
  __syncthreads();
  const int e0 = blockIdx.x * EPB;
  const int e1 = min(e0 + EPB, E);
  for (int e = e0 + t; e < e1; e += 256) {
    int i = is_[(size_t)lay*E + e], j = js_[(size_t)lay*E + e];
    atomicAdd(&h[(i>>7)*32 + (j>>7)], 1u);
  }
  __syncthreads();
  #pragma unroll
  for (int i = 0; i < NBIN_L/256; ++i)
    if (h[t + i*256]) atomicAdd(&hist[lay*NBIN_L + t + i*256], h[t + i*256]);
}

// per-layer scan: block = layer; off base = layer*E (cumsum continuous across layers)
__global__ __launch_bounds__(256) void edge_scan(
    const uint32_t* __restrict__ hist, uint32_t* __restrict__ off,
    uint32_t* __restrict__ cursor, int E)
{
  __shared__ uint32_t sa[NBIN_L], sb[NBIN_L];
  const int lay = blockIdx.x;
  const int t = threadIdx.x;
  const uint32_t base = (uint32_t)lay * (uint32_t)E;
  for (int i = t; i < NBIN_L; i += 256) sa[i] = hist[lay*NBIN_L + i];
  __syncthreads();
  uint32_t* src = sa; uint32_t* dst = sb;
  for (int s = 1; s < NBIN_L; s <<= 1) {
    for (int i = t; i < NBIN_L; i += 256) dst[i] = src[i] + (i >= s ? src[i-s] : 0u);
    __syncthreads();
    uint32_t* tmp = src; src = dst; dst = tmp;
  }
  for (int i = t; i < NBIN_L; i += 256) {
    uint32_t ex = base + (i ? src[i-1] : 0u);
    off[lay*NBIN_L + i] = ex; cursor[lay*NBIN_L + i] = ex;
  }
  if (t == 0 && lay == NLAYERS-1) off[NBIN_T] = base + src[NBIN_L-1];
}

__global__ __launch_bounds__(256) void edge_scatter(
    const int* __restrict__ is_, const int* __restrict__ js_,
    uint32_t* __restrict__ cursor, uint16_t* __restrict__ ebuf, int E)
{
  __shared__ uint32_t h[NBIN_L];
  __shared__ uint32_t basev[NBIN_L];
  const int lay = blockIdx.y;
  const int t = threadIdx.x;
  #pragma unroll
  for (int i = 0; i < NBIN_L/256; ++i) h[t + i*256] = 0u;
  __syncthreads();
  const int e0 = blockIdx.x * EPB;
  const int e1 = min(e0 + EPB, E);
  for (int e = e0 + t; e < e1; e += 256) {
    int i = is_[(size_t)lay*E + e], j = js_[(size_t)lay*E + e];
    atomicAdd(&h[(i>>7)*32 + (j>>7)], 1u);
  }
  __syncthreads();
  #pragma unroll
  for (int i = 0; i < NBIN_L/256; ++i) {
    int b = t + i*256;
    basev[b] = h[b] ? atomicAdd(&cursor[lay*NBIN_L + b], h[b]) : 0u;
    h[b] = 0u;
  }
  __syncthreads();
  for (int e = e0 + t; e < e1; e += 256) {
    int i = is_[(size_t)lay*E + e], j = js_[(size_t)lay*E + e];
    int b = (i>>7)*32 + (j>>7);
    uint32_t r = atomicAdd(&h[b], 1u);
    ebuf[basev[b] + r] = (uint16_t)(((i & 127) << 7) | (j & 127));
  }
}

// ---------------- prep_rows: wave-per-row softmax (+pyramid), fp8 PERMUTED output ----------------
__global__ __launch_bounds__(256) void prep_rows(
    const float* __restrict__ us, const float* __restrict__ vs,
    uint8_t* __restrict__ zt8, uint8_t* __restrict__ wt8, size_t lstride,
    const float* __restrict__ consts, int layer0)
{
  const int t = threadIdx.x, w = t >> 6, l = t & 63;
  const int n = blockIdx.x*4 + w;
  const int layer = layer0 + blockIdx.y;
  const int zmode = (blockIdx.z == 0);
  const float* src = (zmode ? us : vs) + ((size_t)layer*N1 + n)*DD + l*16;
  uint8_t* drow = (zmode ? zt8 : wt8) + (size_t)blockIdx.y*lstride + (size_t)n*1024;
  const int p0 = (l>>2)*64 + ((l&1)*2)*16 + ((l&3)>>1)*8;

  float e[16];
  {
    const float4* s4 = (const float4*)src;
    float4 u0 = s4[0], u1 = s4[1], u2 = s4[2], u3 = s4[3];
    e[0]=u0.x; e[1]=u0.y; e[2]=u0.z; e[3]=u0.w;
    e[4]=u1.x; e[5]=u1.y; e[6]=u1.z; e[7]=u1.w;
    e[8]=u2.x; e[9]=u2.y; e[10]=u2.z; e[11]=u2.w;
    e[12]=u3.x; e[13]=u3.y; e[14]=u3.z; e[15]=u3.w;
  }
  float mx = e[0];
  #pragma unroll
  for (int i = 1; i < 16; ++i) mx = fmaxf(mx, e[i]);
  mx = wredmax(mx);
  float s = 0.f;
  #pragma unroll
  for (int i = 0; i < 16; ++i) { e[i] = __expf(e[i]-mx); s += e[i]; }
  s = wredsum(s);
  float inv = 1.f/s;
  #pragma unroll
  for (int i = 0; i < 16; ++i) e[i] *= inv;

  uint32_t b4[4] = {0u, 0u, 0u, 0u};
  if (!zmode) {
    #pragma unroll
    for (int i = 0; i < 16; ++i)
      b4[i>>2] |= enc_e4m3(e[i]*WSCALE) << ((i&3)*8);
  } else {
    float s1[8], s2[4], s3[2], s4v;
    #pragma unroll
    for (int i = 0; i < 8; ++i) s1[i] = e[2*i] + e[2*i+1];
    #pragma unroll
    for (int i = 0; i < 4; ++i) s2[i] = s1[2*i] + s1[2*i+1];
    s3[0] = s2[0]+s2[1]; s3[1] = s2[2]+s2[3];
    s4v = s3[0]+s3[1];
    float s5 = s4v + __shfl_xor(s4v, 1, 64);
    float s6 = s5  + __shfl_xor(s5, 2, 64);
    float s7 = s6  + __shfl_xor(s6, 4, 64);
    float s8 = s7  + __shfl_xor(s7, 8, 64);
    float s9 = s8  + __shfl_xor(s8, 16, 64);
    const float* pk = consts + 8 + layer*(KKC+1);
    const float base = pk[4]*s4v + pk[5]*s5 + pk[6]*s6 + pk[7]*s7 + pk[8]*s8 + pk[9]*s9;
    const float p1 = pk[1], p2 = pk[2], p3 = pk[3], p10 = pk[10];
    #pragma unroll
    for (int i = 0; i < 16; ++i) {
      float v = p10*e[i] + p1*s1[i>>1] + p2*s2[i>>2] + p3*s3[i>>3] + base;
      b4[i>>2] |= enc_e4m3(v*ZSCALE) << ((i&3)*8);
    }
  }
  uint64_t u0 = (uint64_t)b4[0] | ((uint64_t)b4[1] << 32);
  uint64_t u1 = (uint64_t)b4[2] | ((uint64_t)b4[3] << 32);
  *(uint64_t*)(drow + p0)      = u0;
  *(uint64_t*)(drow + p0 + 16) = u1;
}

// ---------------- 128x128 fp8 GEMM: 4-wave blocks, 4 blocks/CU + fused epilogue (R15/R17 config) ----------------
// 4 waves (2Mx2N), wave tile 64x64, acc[4][4] (64 AGPR + ~64 VGPR = 128 unified, 4 waves/SIMD).
// BK=64B; buf = A 8KB + B 8KB = 16KB; 2 bufs = 32KB dynamic LDS => 4 blocks/CU (128KB).
// Per tile u: {vmcnt(0); s_barrier; 8x ds_read_b128; stage(u+1) [4 gloads]; 32 MFMA}.
// Measured optimum of the ablated family: independent 4-wave barrier domains are the
// binding lever (MfmaUtil 21->38->47%); LDS-BW model closes at 47.4% predicted vs 47.7%.
// Exonerated: prefetch depth (R4/R6/R16), phase interleave (R5/R6), counted vmcnt (R4/R6),
// 6 waves/SIMD (R14: spills), A-from-L2 (R18: VMEM latency on critical path).
__global__ __launch_bounds__(256, 4) void gemm_fused(
    const uint8_t* __restrict__ Az8, size_t zls,
    const uint8_t* __restrict__ Bw8, size_t wls,
    const float* __restrict__ a_tab, const float* __restrict__ b_tab,
    const float* __restrict__ g_tab, const float* __restrict__ d_tab,
    const float* __restrict__ consts, int layer0,
    const uint32_t* __restrict__ eoff, const uint16_t* __restrict__ ebuf,
    float* __restrict__ out)
{
  extern __shared__ char lds[];                // 32KB: 2 x 16KB bufs; epilogue reuses
  const int t = threadIdx.x;
  const int w = t >> 6, l = t & 63;
  const int wm = w >> 1, wn = w & 1;           // 2x2 wave grid; wave tile 64x64
  const int fr = l & 15, fq = l >> 4;

  // T1: bijective XCD swizzle (3072 blocks % 8 == 0)
  const int nbx = gridDim.x, nby = gridDim.y;   // 32, 32
  int lid = blockIdx.x + nbx*(blockIdx.y + nby*blockIdx.z);
  const int nblk = nbx*nby*gridDim.z;
  const int cpx = nblk >> 3;
  int nid = (lid & 7)*cpx + (lid >> 3);
  const int bz = nid / (nbx*nby);
  const int rem = nid % (nbx*nby);
  const int bi = rem % nbx, bj = rem / nbx;

  const int i0 = bi*128, j0 = bj*128;
  const int layer = layer0 + bz;
  Az8 += (size_t)bz*zls + (size_t)i0*1024;
  Bw8 += (size_t)bz*wls + (size_t)j0*1024;

  f32x4 acc[4][4];
  f32x4 zero = {0.f, 0.f, 0.f, 0.f};
  #pragma unroll
  for (int m = 0; m < 4; ++m)
    #pragma unroll
    for (int nn = 0; nn < 4; ++nn) acc[m][nn] = zero;

  // stage-side involution (verified R10-R17)
  const int go = (l & 7) ^ (l >> 3);
  const size_t s_off = (size_t)((l >> 3)*2 + (go >> 2))*1024 + (size_t)(go & 3)*16;
  // read-side slot (conflict-free b128 pattern, verified R11-R17)
  const int slot = (((fr & 1) << 2) + fq) ^ (fr >> 1);
  const int abase = wm*4096 + (fr>>1)*128 + slot*16;          // + m*1024
  const int bbase = 8192 + wn*4096 + (fr>>1)*128 + slot*16;   // + nn*1024

  longx2 ar2[4], br2[4];

#define STG_A(tile) do { \
    char* _d = lds + ((tile)&1)*16384 + w*2048; \
    const uint8_t* _s = Az8 + (size_t)(w*32)*1024 + (size_t)(tile)*64 + s_off; \
    global_load_lds16(_s, _d); \
    global_load_lds16(_s + (size_t)16*1024, _d + 1024); \
  } while (0)
#define STG_B(tile) do { \
    char* _d = lds + ((tile)&1)*16384 + 8192 + w*2048; \
    const uint8_t* _s = Bw8 + (size_t)(w*32)*1024 + (size_t)(tile)*64 + s_off; \
    global_load_lds16(_s, _d); \
    global_load_lds16(_s + (size_t)16*1024, _d + 1024); \
  } while (0)

  // prologue: stage tile 0 into buf0
  STG_A(0); STG_B(0);

  for (int u = 0; u < 16; ++u) {
    const int cb = (u & 1)*16384;
    asm volatile("s_waitcnt vmcnt(0)" ::: "memory");   // own stage(u) landed
    asm volatile("s_barrier" ::: "memory");            // stage(u) visible block-wide
    #pragma unroll
    for (int i = 0; i < 4; ++i)
      ar2[i] = *(const longx2*)(lds + cb + abase + i*1024);
    #pragma unroll
    for (int j = 0; j < 4; ++j)
      br2[j] = *(const longx2*)(lds + cb + bbase + j*1024);
    if (u < 15) { STG_A(u+1); STG_B(u+1); }
    __builtin_amdgcn_s_setprio(1);
    #pragma unroll
    for (int i = 0; i < 4; ++i)
      #pragma unroll
      for (int j = 0; j < 4; ++j) {
        acc[i][j] = __builtin_amdgcn_mfma_f32_16x16x32_fp8_fp8(
            ar2[i].x, br2[j].x, acc[i][j], 0, 0, 0);
        acc[i][j] = __builtin_amdgcn_mfma_f32_16x16x32_fp8_fp8(
            ar2[i].y, br2[j].y, acc[i][j], 0, 0, 0);
      }
    __builtin_amdgcn_s_setprio(0);
  }
#undef STG_A
#undef STG_B

  // ---- epilogue: C (128x128 bf16 = 32KB) into LDS; dense softplus-sum + binned sparse ----
  __syncthreads();                       // all waves done reading staging bufs
  const float cc = consts[layer];
  {
    // row = wm*64 + m*16 + fq*4 + r ; col = wn*64 + nn*16 + fr ; byte = row*256 + col*2
    char* cbase = lds + wm*16384 + fq*1024 + wn*128 + fr*2;
    #pragma unroll
    for (int m = 0; m < 4; ++m)
      #pragma unroll
      for (int nn = 0; nn < 4; ++nn)
        #pragma unroll
        for (int r = 0; r < 4; ++r)
          *(bf16_t*)(cbase + m*4096 + r*256 + nn*32) =
              (bf16_t)(acc[m][nn][r]*INVSCALE + cc);
  }
  __syncthreads();

  const float* at = a_tab + layer*N1;
  const float* bt = b_tab + layer*N2;
  const float* gt = g_tab + layer*N1;
  const float* dt = d_tab + layer*N2;
  float dsum = 0.f;
  #pragma unroll
  for (int i = 0; i < 8; ++i) {
    const int id = t + i*256;            // 2048 chunks of 16B
    const int row = id >> 4, g = id & 15;
    bf16x8 v = *(const bf16x8*)(lds + row*256 + g*16);
    const int grow = i0 + row, gcol = j0 + g*8;
    const float av = at[grow], gv = gt[grow];
    float4 b0 = *(const float4*)(bt + gcol), b1 = *(const float4*)(bt + gcol + 4);
    float4 d0 = *(const float4*)(dt + gcol), d1 = *(const float4*)(dt + gcol + 4);
    float bb[8] = {b0.x,b0.y,b0.z,b0.w,b1.x,b1.y,b1.z,b1.w};
    float dd[8] = {d0.x,d0.y,d0.z,d0.w,d1.x,d1.y,d1.z,d1.w};
    #pragma unroll
    for (int e2 = 0; e2 < 8; ++e2) {
      float x = av*bb[e2]*(float)v[e2] + gv + dd[e2];
      float sp = softplus_fast(x);
      dsum += (grow != gcol + e2) ? sp : 0.f;
    }
  }
  const int bin = bz*NBIN_L + bi*32 + bj;
  const uint32_t e0 = eoff[bin], e1 = eoff[bin+1];
  float ssum = 0.f;
  for (uint32_t e = e0 + (uint32_t)t; e < e1; e += 256u) {
    const int pk2 = ebuf[e];
    const int li = pk2 >> 7, lj = pk2 & 127;
    float dc = (float)*(const bf16_t*)(lds + li*256 + lj*2);
    ssum += at[i0+li]*bt[j0+lj]*dc + gt[i0+li] + dt[j0+lj];
  }
  float tot = wredsum(ssum - dsum);
  __syncthreads();
  if (l == 0) ((float*)lds)[w] = tot;
  __syncthreads();
  if (t == 0) {
    const float* r = (const float*)lds;
    atomicAdd(out, r[0] + r[1] + r[2] + r[3]);   // ll += z_pdist2 - z_pdist1
  }
}

extern "C" void kernel_launch(void* const* d_in, const int* in_sizes, int n_in,
                              void* d_out, int out_size, void* d_ws, size_t ws_size,
                              hipStream_t stream) {
  const float* us    = (const float*)d_in[0];
  const float* vs    = (const float*)d_in[1];
  const float* gamma = (const float*)d_in[2];
  const float* delta = (const float*)d_in[3];
  const float* lz    = (const float*)d_in[4];
  const float* lw    = (const float*)d_in[5];
  const float* pks   = (const float*)d_in[6];
  const float* Lp    = (const float*)d_in[7];
  const int*   sis   = (const int*)d_in[8];
  const int*   sjs   = (const int*)d_in[9];
  float* out = (float*)d_out;
  char*  ws  = (char*)d_ws;
  const int E = in_sizes[8] / NLAYERS;

  size_t p = 0;
  float* consts = (float*)(ws + p); p += 1024;
  float* a_tab  = (float*)(ws + p); p += (size_t)NLAYERS*N1*4;
  float* b_tab  = (float*)(ws + p); p += (size_t)NLAYERS*N2*4;
  float* g_tab  = (float*)(ws + p); p += (size_t)NLAYERS*N1*4;
  float* d_tab  = (float*)(ws + p); p += (size_t)NLAYERS*N2*4;
  uint32_t* hist   = (uint32_t*)(ws + p); p += 4096*4;
  uint32_t* eoff   = (uint32_t*)(ws + p); p += 4096*4;
  uint32_t* cursor = (uint32_t*)(ws + p); p += 4096*4;
  uint16_t* ebuf   = (uint16_t*)(ws + p); p += (size_t)NLAYERS*E*2;
  p = (p + 4095) & ~(size_t)4095;
  uint8_t* zt8 = (uint8_t*)(ws + p); p += (size_t)NLAYERS*N1*1024;
  uint8_t* wt8 = (uint8_t*)(ws + p); p += (size_t)NLAYERS*N2*1024;
  if (ws_size < p) return;
  const size_t ZLS = (size_t)N1*1024;
  const size_t LDSB = 32768;
  const int nebl = (E + EPB - 1) / EPB;

  prep_small<<<(N1+255)/256, 256, 0, stream>>>(lz, lw, gamma, delta, pks, Lp,
                                               consts, a_tab, b_tab, g_tab, d_tab,
                                               hist, out);
  edge_hist<<<dim3(nebl, NLAYERS), 256, 0, stream>>>(sis, sjs, hist, E);
  edge_scan<<<NLAYERS, 256, 0, stream>>>(hist, eoff, cursor, E);
  edge_scatter<<<dim3(nebl, NLAYERS), 256, 0, stream>>>(sis, sjs, cursor, ebuf, E);
  prep_rows<<<dim3(N1/4, NLAYERS, 2), 256, 0, stream>>>(us, vs, zt8, wt8, ZLS, consts, 0);
  gemm_fused<<<dim3(32,32,NLAYERS), 256, LDSB, stream>>>(
      zt8, ZLS, wt8, ZLS, a_tab, b_tab, g_tab, d_tab, consts, 0, eoff, ebuf, out);
}